// Round 7
// baseline (1005.864 us; speedup 1.0000x reference)
//
#include <hip/hip_runtime.h>

#define NB      16
#define NPTS    4096
#define NPOINT  1024
#define NSAMPLE 32

typedef float v2f __attribute__((ext_vector_type(2)));

// ---- packed f32 ops (VOP3P, exact IEEE RN per half; NOT fused) ----
__device__ __forceinline__ v2f pk_add(v2f a, v2f b) {
  v2f d;
  asm("v_pk_add_f32 %0, %1, %2" : "=v"(d) : "v"(a), "v"(b));
  return d;
}
__device__ __forceinline__ v2f pk_mul(v2f a, v2f b) {
  v2f d;
  asm("v_pk_mul_f32 %0, %1, %2" : "=v"(d) : "v"(a), "v"(b));
  return d;
}
__device__ __forceinline__ float fnegx(float x) {  // exact bit-flip negation
  return __int_as_float(__float_as_int(x) ^ 0x80000000);
}

// ---------------- DPP / swizzle u64-key max helpers ----------------
template <int C>
__device__ __forceinline__ int dppi(int v) {
  return __builtin_amdgcn_update_dpp(0, v, C, 0xf, 0xf, true);
}

template <int C>
__device__ __forceinline__ unsigned long long dppmax_u64(unsigned long long k) {
  int lo = dppi<C>((int)(unsigned)k);
  int hi = dppi<C>((int)(k >> 32));
  unsigned long long o = ((unsigned long long)(unsigned)hi << 32) | (unsigned)lo;
  return o > k ? o : k;
}

__device__ __forceinline__ unsigned long long swzmax16_u64(unsigned long long k) {
  int lo = __builtin_amdgcn_ds_swizzle((int)(unsigned)k, 0x401F);  // lane ^= 16
  int hi = __builtin_amdgcn_ds_swizzle((int)(k >> 32), 0x401F);
  unsigned long long o = ((unsigned long long)(unsigned)hi << 32) | (unsigned)lo;
  return o > k ? o : k;
}

// shared view for the fused fps+p1 kernel (block-uniform branch selects view)
union SharedA {
  struct {
    float4 lc4[NPTS];                // padded coords: one ds_read_b128 winner lookup
    float scen[NPOINT * 3];          // center buffer, flushed once at the end
    unsigned long long part[2][16];  // double-buffered partials
  } f;
  float sw[4096];                    // p1: staged W0[3:67]
};

// ---------------------------------------------------------------------------
// Fused FPS + P1. FPS occupies only 16 CUs for ~650us; P1 (independent of
// FPS) runs concurrently on the other CUs' blocks => its whole cost hides.
// blocks 0..15: FPS v7 = v6 + float4 coord array (1 ds_read_b128 lookup).
// blocks 16..143: P1[r,d] = sum_c pts[r,c]*W0[3+c,d], 512 rows/block.
// ---------------------------------------------------------------------------
__global__ __launch_bounds__(512) void fps_p1_kernel(
    const float* __restrict__ xyz, const float* __restrict__ pts,
    const float* __restrict__ W0, float* __restrict__ out_xyz,
    float* __restrict__ P1) {
  __shared__ SharedA sm;
  const int t = threadIdx.x;
  if (blockIdx.x < NB) {
    // ================= FPS =================
    const int b = blockIdx.x;
    const int lane = t & 63;
    const int wid = t >> 6;
    const float* g = xyz + (size_t)b * NPTS * 3;
    for (int j = t; j < NPTS; j += 512)
      sm.f.lc4[j] = make_float4(g[3 * j], g[3 * j + 1], g[3 * j + 2], 0.0f);
    __syncthreads();
    // pair p holds points j = t + 512*(2p) (.x) and j + 512 (.y)
    v2f px2[4], py2[4], pz2[4], mind2[4];
    unsigned nlo[8];
#pragma unroll
    for (int p = 0; p < 4; ++p) {
      const int j0 = t + 512 * (2 * p);
      const float4 a = sm.f.lc4[j0];
      const float4 c = sm.f.lc4[j0 + 512];
      px2[p] = (v2f){a.x, c.x};
      py2[p] = (v2f){a.y, c.y};
      pz2[p] = (v2f){a.z, c.z};
      mind2[p] = (v2f){1e10f, 1e10f};
      nlo[2 * p] = ~(unsigned)j0;
      nlo[2 * p + 1] = ~(unsigned)(j0 + 512);
    }
    float cx, cy, cz;
    {
      const float4 c0 = sm.f.lc4[0];  // far = 0 initially
      cx = c0.x; cy = c0.y; cz = c0.z;
    }
    for (int it = 0; it < NPOINT; ++it) {
      if (t == 0) {  // LDS-only write; flushed to global after the loop
        sm.f.scen[3 * it] = cx; sm.f.scen[3 * it + 1] = cy; sm.f.scen[3 * it + 2] = cz;
      }
      const float ncx = fnegx(cx), ncy = fnegx(cy), ncz = fnegx(cz);
      const v2f ncxx = (v2f){ncx, ncx};
      const v2f ncyy = (v2f){ncy, ncy};
      const v2f nczz = (v2f){ncz, ncz};
      // ---- packed update: d2 = ((dx*dx + dy*dy) + dz*dz), two roundings ----
#pragma unroll
      for (int p = 0; p < 4; ++p) {
        const v2f dx = pk_add(px2[p], ncxx);
        const v2f dy = pk_add(py2[p], ncyy);
        const v2f dz = pk_add(pz2[p], nczz);
        const v2f xx = pk_mul(dx, dx);
        const v2f yy = pk_mul(dy, dy);
        const v2f zz = pk_mul(dz, dz);
        v2f s = pk_add(xx, yy);
        s = pk_add(s, zz);
        mind2[p].x = fminf(mind2[p].x, s.x);
        mind2[p].y = fminf(mind2[p].y, s.y);
      }
      // ---- local argmax: 7-node u64 max tree ----
      unsigned long long k[8];
#pragma unroll
      for (int p = 0; p < 4; ++p) {
        k[2 * p] = ((unsigned long long)__float_as_uint(mind2[p].x) << 32) | nlo[2 * p];
        k[2 * p + 1] =
            ((unsigned long long)__float_as_uint(mind2[p].y) << 32) | nlo[2 * p + 1];
      }
#pragma unroll
      for (int s = 4; s; s >>= 1)
#pragma unroll
        for (int i = 0; i < s; ++i) k[i] = k[i] > k[i + s] ? k[i] : k[i + s];
      // ---- in-wave butterfly: 4 DPP + swz^16 -> 32-lane group max ----
      unsigned long long key = k[0];
      key = dppmax_u64<0xB1>(key);   // xor 1
      key = dppmax_u64<0x4E>(key);   // xor 2
      key = dppmax_u64<0x141>(key);  // half-mirror (covers 8)
      key = dppmax_u64<0x140>(key);  // mirror (covers 16)
      key = swzmax16_u64(key);       // xor 16 -> 32-lane uniform
      const int buf = it & 1;
      if ((lane & 31) == 0) sm.f.part[buf][wid * 2 + (lane >> 5)] = key;
      __syncthreads();
      // ---- final reduce over 16 partials + single b128 coord lookup ----
      unsigned long long rk = sm.f.part[buf][lane & 15];
      rk = dppmax_u64<0xB1>(rk);   // xor 1
      rk = dppmax_u64<0x4E>(rk);   // xor 2
      rk = dppmax_u64<0x141>(rk);  // covers 8
      rk = dppmax_u64<0x140>(rk);  // covers 16
      const unsigned idx = ~(unsigned)rk;  // winner index (block-uniform)
      const float4 c4 = sm.f.lc4[idx];     // ONE broadcast ds_read_b128
      cx = c4.x; cy = c4.y; cz = c4.z;
    }
    __syncthreads();
    float* ob = out_xyz + (size_t)b * NPOINT * 3;
    for (int i = t; i < NPOINT * 3; i += 512) ob[i] = sm.f.scen[i];
  } else {
    // ================= P1 =================
    {
      const float4* w4 = (const float4*)(W0 + 192);
      float4* s4 = (float4*)sm.sw;
#pragma unroll
      for (int m = 0; m < 2; ++m) s4[t + 512 * m] = w4[t + 512 * m];
    }
    __syncthreads();
    const size_t r = (size_t)(blockIdx.x - NB) * 512 + t;
    const float* prow = pts + r * 64;
    float acc[64];
#pragma unroll
    for (int d = 0; d < 64; ++d) acc[d] = 0.0f;
#pragma unroll
    for (int cq = 0; cq < 16; ++cq) {
      const float4 p4 = *(const float4*)(prow + cq * 4);
      const float pv[4] = {p4.x, p4.y, p4.z, p4.w};
#pragma unroll
      for (int u = 0; u < 4; ++u) {
        const int c = cq * 4 + u;
#pragma unroll
        for (int d4 = 0; d4 < 16; ++d4) {
          const float4 w = *(const float4*)(&sm.sw[c * 64 + d4 * 4]);
          acc[d4 * 4 + 0] = fmaf(pv[u], w.x, acc[d4 * 4 + 0]);
          acc[d4 * 4 + 1] = fmaf(pv[u], w.y, acc[d4 * 4 + 1]);
          acc[d4 * 4 + 2] = fmaf(pv[u], w.z, acc[d4 * 4 + 2]);
          acc[d4 * 4 + 3] = fmaf(pv[u], w.w, acc[d4 * 4 + 3]);
        }
      }
    }
    float* o = P1 + r * 64;
#pragma unroll
    for (int d4 = 0; d4 < 16; ++d4)
      *(float4*)(o + d4 * 4) =
          make_float4(acc[d4 * 4], acc[d4 * 4 + 1], acc[d4 * 4 + 2], acc[d4 * 4 + 3]);
  }
}

// ---------------------------------------------------------------------------
// Fused ball-query + MLP + maxpool. Phase 1: 4 waves scan 2 queries each
// (ballot + prefix popcount, early exit), idx kept in LDS (no global
// round-trip); writes out_idx floats. Phase 2: thread = (query, sample),
// MLP with global scalar-path weights, k-max via __shfl_xor.
// ---------------------------------------------------------------------------
__global__ __launch_bounds__(256) void ballq_mlp_kernel(
    const float* __restrict__ xyz, const float* __restrict__ new_xyz,
    const float* __restrict__ P1,
    const float* __restrict__ W0, const float* __restrict__ b0,
    const float* __restrict__ W1, const float* __restrict__ b1,
    const float* __restrict__ W2, const float* __restrict__ b2,
    float* __restrict__ out_np, float* __restrict__ out_idx) {
  __shared__ int sidx[8][NSAMPLE];
  const int t = threadIdx.x;
  const int wv = t >> 6, lane = t & 63;
  const int qbase = blockIdx.x * 8;
  const float r2 = (float)(0.2 * 0.2);  // double->f32 (NOT 0.2f*0.2f)
  // ---- phase 1: ball query, 2 queries per wave ----
  for (int s = 0; s < 2; ++s) {
    const int ql = wv * 2 + s;
    const int q = qbase + ql;
    const int b = q >> 10;
    const float* g = xyz + (size_t)b * NPTS * 3;
    const float nx = new_xyz[(size_t)q * 3];
    const float ny = new_xyz[(size_t)q * 3 + 1];
    const float nz = new_xyz[(size_t)q * 3 + 2];
    int cnt = 0;
    for (int base = 0; base < NPTS; base += 64) {
      const int j = base + lane;
      const float dx = __fsub_rn(g[3 * j], nx);
      const float dy = __fsub_rn(g[3 * j + 1], ny);
      const float dz = __fsub_rn(g[3 * j + 2], nz);
      const float d2 = __fadd_rn(__fadd_rn(__fmul_rn(dx, dx), __fmul_rn(dy, dy)),
                                 __fmul_rn(dz, dz));
      const bool hit = d2 <= r2;
      const unsigned long long m = __ballot(hit);
      const int pos = cnt + __popcll(m & ((1ull << lane) - 1ull));
      if (hit && pos < NSAMPLE) sidx[ql][pos] = j;
      cnt += __popcll(m);
      if (cnt >= NSAMPLE) break;  // wave-uniform
    }
    const int capped = cnt < NSAMPLE ? cnt : NSAMPLE;
    if (lane < NSAMPLE) {
      const int v = sidx[ql][lane < capped ? lane : 0];  // pad with first hit
      sidx[ql][lane] = v;
      out_idx[(size_t)q * NSAMPLE + lane] = (float)v;
    }
  }
  __syncthreads();
  // ---- phase 2: MLP + maxpool ----
  const int k = t & 31;
  const int ql = t >> 5;
  const int q = qbase + ql;
  const int b = q >> 10;
  const int idx = sidx[ql][k];
  const float nx = new_xyz[(size_t)q * 3];
  const float ny = new_xyz[(size_t)q * 3 + 1];
  const float nz = new_xyz[(size_t)q * 3 + 2];
  const float* p = xyz + ((size_t)b * NPTS + idx) * 3;
  const float dx = p[0] - nx, dy = p[1] - ny, dz = p[2] - nz;

  float h1[64];
  const float* p1r = P1 + ((size_t)b * NPTS + idx) * 64;
#pragma unroll
  for (int d4 = 0; d4 < 16; ++d4) {
    const float4 pv = *(const float4*)(p1r + d4 * 4);
    const float pe[4] = {pv.x, pv.y, pv.z, pv.w};
#pragma unroll
    for (int u = 0; u < 4; ++u) {
      const int d = d4 * 4 + u;
      const float v = pe[u] + dx * W0[d] + dy * W0[64 + d] + dz * W0[128 + d] + b0[d];
      h1[d] = fmaxf(v, 0.0f);
    }
  }

  float h2[64];
#pragma unroll
  for (int j4 = 0; j4 < 16; ++j4) {
    const float4 bb = *(const float4*)(&b1[j4 * 4]);
    h2[j4 * 4 + 0] = bb.x; h2[j4 * 4 + 1] = bb.y;
    h2[j4 * 4 + 2] = bb.z; h2[j4 * 4 + 3] = bb.w;
  }
#pragma unroll
  for (int c = 0; c < 64; ++c) {
    const float hc = h1[c];
#pragma unroll
    for (int j4 = 0; j4 < 16; ++j4) {
      const float4 w = *(const float4*)(&W1[c * 64 + j4 * 4]);
      h2[j4 * 4 + 0] = fmaf(hc, w.x, h2[j4 * 4 + 0]);
      h2[j4 * 4 + 1] = fmaf(hc, w.y, h2[j4 * 4 + 1]);
      h2[j4 * 4 + 2] = fmaf(hc, w.z, h2[j4 * 4 + 2]);
      h2[j4 * 4 + 3] = fmaf(hc, w.w, h2[j4 * 4 + 3]);
    }
  }
#pragma unroll
  for (int j = 0; j < 64; ++j) h2[j] = fmaxf(h2[j], 0.0f);

  float* outq = out_np + (size_t)q * 128;
  for (int jb = 0; jb < 4; ++jb) {
    float acc[32];
#pragma unroll
    for (int j8 = 0; j8 < 8; ++j8) {
      const float4 bb = *(const float4*)(&b2[jb * 32 + j8 * 4]);
      acc[j8 * 4 + 0] = bb.x; acc[j8 * 4 + 1] = bb.y;
      acc[j8 * 4 + 2] = bb.z; acc[j8 * 4 + 3] = bb.w;
    }
#pragma unroll
    for (int c = 0; c < 64; ++c) {
      const float hc = h2[c];
#pragma unroll
      for (int j8 = 0; j8 < 8; ++j8) {
        const float4 w = *(const float4*)(&W2[c * 128 + jb * 32 + j8 * 4]);
        acc[j8 * 4 + 0] = fmaf(hc, w.x, acc[j8 * 4 + 0]);
        acc[j8 * 4 + 1] = fmaf(hc, w.y, acc[j8 * 4 + 1]);
        acc[j8 * 4 + 2] = fmaf(hc, w.z, acc[j8 * 4 + 2]);
        acc[j8 * 4 + 3] = fmaf(hc, w.w, acc[j8 * 4 + 3]);
      }
    }
#pragma unroll
    for (int j = 0; j < 32; ++j) acc[j] = fmaxf(acc[j], 0.0f);
#pragma unroll
    for (int msk = 16; msk >= 1; msk >>= 1) {
#pragma unroll
      for (int j = 0; j < 32; ++j) acc[j] = fmaxf(acc[j], __shfl_xor(acc[j], msk, 64));
    }
    if (k == 0) {
#pragma unroll
      for (int j8 = 0; j8 < 8; ++j8)
        *(float4*)(outq + jb * 32 + j8 * 4) =
            make_float4(acc[j8 * 4 + 0], acc[j8 * 4 + 1], acc[j8 * 4 + 2], acc[j8 * 4 + 3]);
    }
  }
}

extern "C" void kernel_launch(void* const* d_in, const int* in_sizes, int n_in,
                              void* d_out, int out_size, void* d_ws, size_t ws_size,
                              hipStream_t stream) {
  const float* xyz = (const float*)d_in[0];
  const float* pts = (const float*)d_in[1];
  const float* W0  = (const float*)d_in[2];
  const float* b0  = (const float*)d_in[3];
  const float* W1  = (const float*)d_in[4];
  const float* b1  = (const float*)d_in[5];
  const float* W2  = (const float*)d_in[6];
  const float* b2  = (const float*)d_in[7];

  float* out      = (float*)d_out;
  float* out_xyz  = out;                       // [16,1024,3]
  float* out_np   = out + 16 * 1024 * 3;       // [16,1024,128]
  float* out_idx  = out_np + 16 * 1024 * 128;  // [16,1024,32] as float values

  float* P1 = (float*)d_ws;  // 16 MB

  // blocks 0..15 FPS (16 CUs for ~650us) + blocks 16..143 P1 (hidden).
  fps_p1_kernel<<<NB + 128, 512, 0, stream>>>(xyz, pts, W0, out_xyz, P1);
  ballq_mlp_kernel<<<2048, 256, 0, stream>>>(xyz, out_xyz, P1,
                                             W0, b0, W1, b1, W2, b2,
                                             out_np, out_idx);
}